// Round 1
// baseline (68.311 us; speedup 1.0000x reference)
//
#include <hip/hip_runtime.h>

// Problem constants (match reference file)
#define Bn  4
#define Cn  3
#define Hn  224
#define Wn  224
#define Kn  196
#define En  768
#define HW  (Hn * Wn)            // 50176 pixels per (b,c) plane
#define BPB 49                   // blocks per batch in pooling kernel
#define PIX_PER_BLOCK (HW / BPB) // 1024
#define KC  (Kn * Cn)            // 588 accumulator slots per batch

// Kernel 1: segmented sum. Each block owns 1024 contiguous pixels of one
// batch. LDS histogram (588 floats) -> global atomic flush (49-way
// contention per address, trivial).
__global__ __launch_bounds__(256) void seg_pool_kernel(
    const float* __restrict__ img,      // (B,C,H,W)
    const int*   __restrict__ seg,      // (B,H,W)
    float*       __restrict__ pooled)   // (B,K,C) raw sums, pre-zeroed
{
    __shared__ float acc[KC];
    const int tid = threadIdx.x;
    for (int i = tid; i < KC; i += 256) acc[i] = 0.0f;
    __syncthreads();

    const int batch = blockIdx.x / BPB;
    const int blk   = blockIdx.x % BPB;
    const int p0    = blk * PIX_PER_BLOCK;

    const float* img0 = img + (size_t)batch * Cn * HW;
    const int*   seg0 = seg + (size_t)batch * HW;

    #pragma unroll
    for (int i = 0; i < PIX_PER_BLOCK; i += 256) {
        const int   p  = p0 + i + tid;
        const int   k  = seg0[p];            // in [0, K)
        const float v0 = img0[p];            // c = 0 plane
        const float v1 = img0[HW + p];       // c = 1 plane
        const float v2 = img0[2 * HW + p];   // c = 2 plane
        atomicAdd(&acc[k * 3 + 0], v0);      // ds_add_f32, no-return
        atomicAdd(&acc[k * 3 + 1], v1);
        atomicAdd(&acc[k * 3 + 2], v2);
    }
    __syncthreads();

    float* out0 = pooled + (size_t)batch * KC;
    for (int i = tid; i < KC; i += 256) atomicAdd(&out0[i], acc[i]);
}

// Kernel 2: out[b,k,e] = (1/HW) * sum_c pooled[b,k,c] * W[c,e] + bias[e]
// One thread per float4 of output. 602112/4 = 150528 threads = 588 blocks.
__global__ __launch_bounds__(256) void embed_kernel(
    const float* __restrict__ pooled,   // (B,K,C) raw sums
    const float* __restrict__ Wm,       // (C,E)
    const float* __restrict__ bias,     // (E,)
    float*       __restrict__ out)      // (B,K,E)
{
    const float inv = 1.0f / (float)HW;
    const int t  = blockIdx.x * 256 + threadIdx.x;  // [0, B*K*E/4)
    const int e4 = t % (En / 4);
    const int bk = t / (En / 4);

    const float p0 = pooled[bk * 3 + 0] * inv;
    const float p1 = pooled[bk * 3 + 1] * inv;
    const float p2 = pooled[bk * 3 + 2] * inv;

    const float4 w0 = ((const float4*)(Wm          ))[e4];
    const float4 w1 = ((const float4*)(Wm +     En ))[e4];
    const float4 w2 = ((const float4*)(Wm + 2 * En ))[e4];
    const float4 bb = ((const float4*)bias)[e4];

    float4 r;
    r.x = p0 * w0.x + p1 * w1.x + p2 * w2.x + bb.x;
    r.y = p0 * w0.y + p1 * w1.y + p2 * w2.y + bb.y;
    r.z = p0 * w0.z + p1 * w1.z + p2 * w2.z + bb.z;
    r.w = p0 * w0.w + p1 * w1.w + p2 * w2.w + bb.w;
    ((float4*)out)[t] = r;
}

extern "C" void kernel_launch(void* const* d_in, const int* in_sizes, int n_in,
                              void* d_out, int out_size, void* d_ws, size_t ws_size,
                              hipStream_t stream) {
    const float* img  = (const float*)d_in[0];  // (4,3,224,224) fp32
    const int*   seg  = (const int*)  d_in[1];  // (4,224,224) int32
    const float* Wm   = (const float*)d_in[2];  // (3,768) fp32
    const float* bias = (const float*)d_in[3];  // (768,) fp32
    float* out    = (float*)d_out;              // (4,196,768) fp32
    float* pooled = (float*)d_ws;               // B*K*C = 2352 floats scratch

    // d_ws is re-poisoned (0xAA) before every replay: must zero each call.
    hipMemsetAsync(pooled, 0, (size_t)Bn * KC * sizeof(float), stream);

    seg_pool_kernel<<<Bn * BPB, 256, 0, stream>>>(img, seg, pooled);

    // B*K*E/4 / 256 = 602112/1024 = 588 blocks, exact
    embed_kernel<<<(Bn * Kn * En / 4) / 256, 256, 0, stream>>>(pooled, Wm, bias, out);
}

// Round 2
// 66.370 us; speedup vs baseline: 1.0293x; 1.0293x over previous
//
#include <hip/hip_runtime.h>

// Problem constants (match reference file)
#define Bn  4
#define Cn  3
#define Hn  224
#define Wn  224
#define Kn  196
#define En  768
#define HW  (Hn * Wn)            // 50176 pixels per (b,c) plane
#define BPB 49                   // pooling blocks per batch
#define NPOOL (Bn * BPB)         // 196 pooling blocks total
#define KC  (Kn * Cn)            // 588 histogram slots per block

// Kernel 1: per-block segmented partial sums. Each block owns 1024
// contiguous pixels of one batch (256 threads x 4 pixels, int4/float4
// loads). LDS histogram (588 floats), then a plain float4 store of the
// whole histogram to this block's private row of `partials` — no global
// atomics, no pre-zeroing of workspace required (every byte overwritten).
__global__ __launch_bounds__(256) void seg_pool_partial(
    const float* __restrict__ img,       // (B,C,H,W)
    const int*   __restrict__ seg,       // (B,H,W)
    float*       __restrict__ partials)  // (NPOOL, KC)
{
    __shared__ float acc[KC];
    const int tid = threadIdx.x;
    for (int i = tid; i < KC; i += 256) acc[i] = 0.0f;
    __syncthreads();

    const int batch = blockIdx.x / BPB;
    const int blk   = blockIdx.x % BPB;
    const int p4    = blk * 256 + tid;   // float4 index within a plane

    const int4*   seg4 = (const int4*)(seg + (size_t)batch * HW);
    const float4* im   = (const float4*)(img + (size_t)batch * Cn * HW);

    const int4   s  = seg4[p4];
    const float4 v0 = im[p4];                 // c = 0 plane
    const float4 v1 = im[HW / 4 + p4];        // c = 1 plane
    const float4 v2 = im[2 * (HW / 4) + p4];  // c = 2 plane

    atomicAdd(&acc[s.x * 3 + 0], v0.x);
    atomicAdd(&acc[s.x * 3 + 1], v1.x);
    atomicAdd(&acc[s.x * 3 + 2], v2.x);
    atomicAdd(&acc[s.y * 3 + 0], v0.y);
    atomicAdd(&acc[s.y * 3 + 1], v1.y);
    atomicAdd(&acc[s.y * 3 + 2], v2.y);
    atomicAdd(&acc[s.z * 3 + 0], v0.z);
    atomicAdd(&acc[s.z * 3 + 1], v1.z);
    atomicAdd(&acc[s.z * 3 + 2], v2.z);
    atomicAdd(&acc[s.w * 3 + 0], v0.w);
    atomicAdd(&acc[s.w * 3 + 1], v1.w);
    atomicAdd(&acc[s.w * 3 + 2], v2.w);
    __syncthreads();

    float4* dst = (float4*)(partials + (size_t)blockIdx.x * KC);
    if (tid < KC / 4) dst[tid] = ((const float4*)acc)[tid];  // 147 float4
}

// Kernel 2: one block per (b,k). Reduce the 49 partials x 3 channels in
// LDS, then out[b,k,e] = (1/HW) * sum_c pooled_c * W[c,e] + bias[e].
// 192 threads = 3 waves; each thread writes one float4 (768 = 192*4).
__global__ __launch_bounds__(192) void embed_kernel(
    const float* __restrict__ partials,  // (NPOOL, KC)
    const float* __restrict__ Wm,        // (C,E)
    const float* __restrict__ bias,      // (E,)
    float*       __restrict__ out)       // (B,K,E)
{
    __shared__ float part[BPB * 3];   // 147
    __shared__ float sums[3];
    const int b   = blockIdx.x / Kn;
    const int k   = blockIdx.x % Kn;
    const int tid = threadIdx.x;

    if (tid < BPB * 3) {
        const int j = tid / 3;        // which partial block of this batch
        const int c = tid % 3;        // channel
        part[tid] = partials[(size_t)(b * BPB + j) * KC + k * 3 + c];
    }
    __syncthreads();

    if (tid < 3) {
        float s = 0.0f;
        #pragma unroll
        for (int j = 0; j < BPB; ++j) s += part[j * 3 + tid];
        sums[tid] = s * (1.0f / (float)HW);
    }
    __syncthreads();

    const float p0 = sums[0];
    const float p1 = sums[1];
    const float p2 = sums[2];

    const float4 w0 = ((const float4*)(Wm          ))[tid];
    const float4 w1 = ((const float4*)(Wm +     En ))[tid];
    const float4 w2 = ((const float4*)(Wm + 2 * En ))[tid];
    const float4 bb = ((const float4*)bias)[tid];

    float4 r;
    r.x = p0 * w0.x + p1 * w1.x + p2 * w2.x + bb.x;
    r.y = p0 * w0.y + p1 * w1.y + p2 * w2.y + bb.y;
    r.z = p0 * w0.z + p1 * w1.z + p2 * w2.z + bb.z;
    r.w = p0 * w0.w + p1 * w1.w + p2 * w2.w + bb.w;
    ((float4*)out)[(size_t)blockIdx.x * (En / 4) + tid] = r;
}

extern "C" void kernel_launch(void* const* d_in, const int* in_sizes, int n_in,
                              void* d_out, int out_size, void* d_ws, size_t ws_size,
                              hipStream_t stream) {
    const float* img  = (const float*)d_in[0];  // (4,3,224,224) fp32
    const int*   seg  = (const int*)  d_in[1];  // (4,224,224) int32
    const float* Wm   = (const float*)d_in[2];  // (3,768) fp32
    const float* bias = (const float*)d_in[3];  // (768,) fp32
    float* out      = (float*)d_out;            // (4,196,768) fp32
    float* partials = (float*)d_ws;             // (196,588) floats, fully overwritten

    seg_pool_partial<<<NPOOL, 256, 0, stream>>>(img, seg, partials);
    embed_kernel<<<Bn * Kn, 192, 0, stream>>>(partials, Wm, bias, out);
}